// Round 1
// 183.340 us; speedup vs baseline: 1.0627x; 1.0627x over previous
//
#include <hip/hip_runtime.h>

typedef _Float16 f16;
typedef _Float16 f16x8 __attribute__((ext_vector_type(8)));
typedef float f32x4 __attribute__((ext_vector_type(4)));

#define BK 32

// Async global->LDS, 16B per lane: lane i's 16B lands at base + i*16.
__device__ __forceinline__ void g2l16(const f16* g, f16* l) {
    __builtin_amdgcn_global_load_lds(
        (const __attribute__((address_space(1))) void*)g,
        (__attribute__((address_space(3))) void*)l, 16, 0, 0);
}

__device__ __forceinline__ float soft1(float a, float thr, float w, float s) {
    return copysignf(fmaxf(a - thr, 0.0f), w) * s;
}

__device__ __forceinline__ float thr4(float a0, float a1, float a2, float a3) {
    float lo01 = fminf(a0, a1), hi01 = fmaxf(a0, a1);
    float lo23 = fminf(a2, a3), hi23 = fmaxf(a2, a3);
    return fminf(fmaxf(lo01, lo23), fminf(hi01, hi23));
}

// One launch: [0, nCastB)        -> cast x fp32 -> f16
//             [nCastB, +nSpInB)  -> sparsify w_in   (2:4 along R), out winT  [R][D]
//             [.., +nSpOutB)     -> sparsify w_out^T (2:4 along D), out woutT [D][R]
__global__ __launch_bounds__(256) void prep_kernel(
    const float* __restrict__ x, f16* __restrict__ xh, int n8,
    const float* __restrict__ Wi, f16* __restrict__ winT, const float* __restrict__ sci,
    const float* __restrict__ Wo, f16* __restrict__ woutT, const float* __restrict__ sco,
    int D, int R, int nCastB, int nSpInB)
{
    int b = blockIdx.x;
    int tid = threadIdx.x;
    if (b < nCastB) {
        int i = b * 256 + tid;
        if (i < n8) {
            float4 a = reinterpret_cast<const float4*>(x)[2 * i];
            float4 c = reinterpret_cast<const float4*>(x)[2 * i + 1];
            f16x8 o = {(f16)a.x, (f16)a.y, (f16)a.z, (f16)a.w,
                       (f16)c.x, (f16)c.y, (f16)c.z, (f16)c.w};
            reinterpret_cast<f16x8*>(xh)[i] = o;
        }
    } else if (b < nCastB + nSpInB) {
        int t = (b - nCastB) * 256 + tid;   // t = rg*D + d (coalesced writes)
        int RG = R >> 2;
        if (t >= RG * D) return;
        int rg = t / D, d = t - rg * D;
        float s = *sci;
        float4 w = *reinterpret_cast<const float4*>(Wi + (size_t)d * R + rg * 4);
        float a0 = fabsf(w.x), a1 = fabsf(w.y), a2 = fabsf(w.z), a3 = fabsf(w.w);
        float thr = thr4(a0, a1, a2, a3);
        size_t base = (size_t)(rg * 4) * D + d;
        winT[base]                 = (f16)soft1(a0, thr, w.x, s);
        winT[base + D]             = (f16)soft1(a1, thr, w.y, s);
        winT[base + 2 * (size_t)D] = (f16)soft1(a2, thr, w.z, s);
        winT[base + 3 * (size_t)D] = (f16)soft1(a3, thr, w.w, s);
    } else {
        int t = (b - nCastB - nSpInB) * 256 + tid;  // t = dg*R + r
        if (t >= (D >> 2) * R) return;
        int dg = t / R, r = t - dg * R;
        float s = *sco;
        size_t i0 = (size_t)(dg * 4) * R + r;
        float w0 = Wo[i0], w1 = Wo[i0 + R], w2 = Wo[i0 + 2 * (size_t)R], w3 = Wo[i0 + 3 * (size_t)R];
        float a0 = fabsf(w0), a1 = fabsf(w1), a2 = fabsf(w2), a3 = fabsf(w3);
        float thr = thr4(a0, a1, a2, a3);
        woutT[i0]                 = (f16)soft1(a0, thr, w0, s);
        woutT[i0 + R]             = (f16)soft1(a1, thr, w1, s);
        woutT[i0 + 2 * (size_t)R] = (f16)soft1(a2, thr, w2, s);
        woutT[i0 + 3 * (size_t)R] = (f16)soft1(a3, thr, w3, s);
    }
}

// C[M][N] = A[M][K] f16 @ Bt[N][K]^T f16, fp32 accum.
// Tile TBM x TBN, 4 waves in 2x2 grid (wave tile TBM/2 x TBN/2).
// Double-buffered LDS (T3 minimum 2-phase): STAGE(t+1) issued BEFORE
// compute(t), so the vmcnt(0) drain inside __syncthreads() lands after
// ds_read+MFMA have covered most of the global-load latency.
// 1-D grid, XCD-aware bijective swizzle: each XCD owns a contiguous band
// of M-tiles (all N-tiles) -> A rows fetched once per XCD L2.
template <int TBM, int TBN, typename OT, bool BIAS>
__global__ __launch_bounds__(256) void gemm_bt(
    const f16* __restrict__ A, const f16* __restrict__ Bt, OT* __restrict__ C,
    const float* __restrict__ bias, int M, int N, int K)
{
    constexpr int MI = TBM / 32;   // A-fragments per wave
    constexpr int NF = TBN / 32;   // B-fragments per wave
    constexpr int HM = TBM / 2;    // per-wave M span
    constexpr int HN = TBN / 2;    // per-wave N span
    __shared__ f16 As[2][TBM * BK];
    __shared__ f16 Bs[2][TBN * BK];

    const int tid  = threadIdx.x;
    const int lane = tid & 63;
    const int w    = tid >> 6;
    const int wm   = w & 1;
    const int wn   = w >> 1;
    const int l16  = lane & 15;
    const int quad = lane >> 4;

    // XCD swizzle: HW round-robins consecutive dispatches across 8 XCDs.
    // wgid = (d%8)*(nb/8) + d/8 gives XCD r the contiguous tile range
    // [r*nb/8, (r+1)*nb/8) -> (with bx fastest) nby/8 M-bands x all bx.
    const int nbx = N / TBN;
    const int nb  = gridDim.x;
    int d = blockIdx.x;
    int wgid = ((nb & 7) == 0) ? ((d & 7) * (nb >> 3) + (d >> 3)) : d;
    int by = wgid / nbx;
    int bx = wgid - by * nbx;
    const int bm = by * TBM;
    const int bn = bx * TBN;

    // one g2l16 by a full wave covers 16 rows x 32 halves:
    // row = lane>>2, col = (lane&3)*8
    const int srow = lane >> 2;
    const int scol = (lane & 3) * 8;
    const f16* gA = A  + (size_t)(bm + w * (TBM / 4) + srow) * K + scol;
    const f16* gB = Bt + (size_t)(bn + w * (TBN / 4) + srow) * K + scol;

    f32x4 acc[MI][NF] = {};

    auto STAGE = [&](int buf, int k0) {
        f16* lA = &As[buf][(w * (TBM / 4)) * BK];
        f16* lB = &Bs[buf][(w * (TBN / 4)) * BK];
#pragma unroll
        for (int i = 0; i < TBM / 64; ++i)
            g2l16(gA + k0 + i * 16 * (size_t)K, lA + i * 16 * BK);
#pragma unroll
        for (int i = 0; i < TBN / 64; ++i)
            g2l16(gB + k0 + i * 16 * (size_t)K, lB + i * 16 * BK);
        // keep prefetch issue ahead of the compute phase
        __builtin_amdgcn_sched_barrier(0);
    };

    auto COMPUTE = [&](int buf) {
        f16x8 af[MI], bf[NF];
#pragma unroll
        for (int m = 0; m < MI; ++m)
            af[m] = *reinterpret_cast<const f16x8*>(
                &As[buf][(wm * HM + m * 16 + l16) * BK + quad * 8]);
#pragma unroll
        for (int n = 0; n < NF; ++n)
            bf[n] = *reinterpret_cast<const f16x8*>(
                &Bs[buf][(wn * HN + n * 16 + l16) * BK + quad * 8]);
#pragma unroll
        for (int m = 0; m < MI; ++m)
#pragma unroll
            for (int n = 0; n < NF; ++n)
                acc[m][n] = __builtin_amdgcn_mfma_f32_16x16x32_f16(af[m], bf[n], acc[m][n], 0, 0, 0);
    };

    const int nk = K / BK;   // even (64 for GEMM1, 16 for GEMM2)
    STAGE(0, 0);
    __syncthreads();
    for (int t = 0; t < nk - 2; t += 2) {
        STAGE(1, (t + 1) * BK);   // prefetch next tile (overlaps compute)
        COMPUTE(0);
        __syncthreads();          // vmcnt(0)+lgkmcnt(0)+barrier: tile t+1 ready
        STAGE(0, (t + 2) * BK);
        COMPUTE(1);
        __syncthreads();
    }
    STAGE(1, (nk - 1) * BK);
    COMPUTE(0);
    __syncthreads();
    COMPUTE(1);

    // epilogue: C/D layout row = quad*4 + r, col = lane&15
#pragma unroll
    for (int m = 0; m < MI; ++m) {
        int row_base = bm + wm * HM + m * 16 + quad * 4;
#pragma unroll
        for (int n = 0; n < NF; ++n) {
            int col = bn + wn * HN + n * 16 + l16;
            float b = BIAS ? bias[col] : 0.0f;
#pragma unroll
            for (int r = 0; r < 4; ++r) {
                float v = acc[m][n][r];
                size_t idx = (size_t)(row_base + r) * N + col;
                if constexpr (BIAS) C[idx] = (OT)(v + b);
                else                C[idx] = (OT)v;
            }
        }
    }
}

extern "C" void kernel_launch(void* const* d_in, const int* in_sizes, int n_in,
                              void* d_out, int out_size, void* d_ws, size_t ws_size,
                              hipStream_t stream)
{
    const float* x      = (const float*)d_in[0];
    const float* w_in   = (const float*)d_in[1];
    const float* w_out  = (const float*)d_in[2];
    const float* bias   = (const float*)d_in[3];
    const float* sc_in  = (const float*)d_in[4];
    const float* sc_out = (const float*)d_in[5];

    const int D = in_sizes[3];            // 2048
    const int R = in_sizes[1] / D;        // 512
    const int M = in_sizes[0] / D;        // 8192 (B*S)

    f16* winT  = (f16*)d_ws;                      // [R][D]
    f16* woutT = winT + (size_t)R * D;            // [D][R]
    f16* h     = woutT + (size_t)D * R;           // [M][R]
    f16* xh    = h + (size_t)M * R;               // [M][D]
    float* out = (float*)d_out;

    const int n8 = M * D / 8;
    const int nCastB  = (n8 + 255) / 256;
    const int nSpInB  = ((R / 4) * D + 255) / 256;
    const int nSpOutB = ((D / 4) * R + 255) / 256;
    prep_kernel<<<nCastB + nSpInB + nSpOutB, 256, 0, stream>>>(
        x, xh, n8, w_in, winT, sc_in, w_out, woutT, sc_out, D, R, nCastB, nSpInB);

    // GEMM1: M=8192, N=512, K=2048. TBN=128 halves A re-reads (8x->4x);
    // grid 4x128 = 512 blocks = 2/CU, dbuf pipeline covers the latency.
    gemm_bt<64, 128, f16, false><<<(R / 128) * (M / 64), 256, 0, stream>>>(
        xh, winT, h, nullptr, M, R, D);
    // GEMM2: M=8192, N=2048, K=512. grid 16x128 = 2048 blocks; per-XCD
    // working set (1MB h-band + 2MB woutT) is L2-resident after swizzle.
    gemm_bt<64, 128, float, true><<<(D / 128) * (M / 64), 256, 0, stream>>>(
        h, woutT, out, bias, M, D, R);
}

// Round 2
// 177.964 us; speedup vs baseline: 1.0948x; 1.0302x over previous
//
#include <hip/hip_runtime.h>

typedef _Float16 f16;
typedef _Float16 f16x8 __attribute__((ext_vector_type(8)));
typedef float f32x4 __attribute__((ext_vector_type(4)));

#define BK 32

// Async global->LDS, 16B per lane: lane i's 16B lands at base + i*16.
__device__ __forceinline__ void g2l16(const f16* g, f16* l) {
    __builtin_amdgcn_global_load_lds(
        (const __attribute__((address_space(1))) void*)g,
        (__attribute__((address_space(3))) void*)l, 16, 0, 0);
}

// Counted vmcnt wait (literal required in asm string).
template <int N> __device__ __forceinline__ void wait_vmcnt();
template <> __device__ __forceinline__ void wait_vmcnt<0>() { asm volatile("s_waitcnt vmcnt(0)" ::: "memory"); }
template <> __device__ __forceinline__ void wait_vmcnt<3>() { asm volatile("s_waitcnt vmcnt(3)" ::: "memory"); }
template <> __device__ __forceinline__ void wait_vmcnt<4>() { asm volatile("s_waitcnt vmcnt(4)" ::: "memory"); }

__device__ __forceinline__ float soft1(float a, float thr, float w, float s) {
    return copysignf(fmaxf(a - thr, 0.0f), w) * s;
}

__device__ __forceinline__ float thr4(float a0, float a1, float a2, float a3) {
    float lo01 = fminf(a0, a1), hi01 = fmaxf(a0, a1);
    float lo23 = fminf(a2, a3), hi23 = fmaxf(a2, a3);
    return fminf(fmaxf(lo01, lo23), fminf(hi01, hi23));
}

// One launch: [0, nCastB)        -> cast x fp32 -> f16
//             [nCastB, +nSpInB)  -> sparsify w_in   (2:4 along R), out winT  [R][D]
//             [.., +nSpOutB)     -> sparsify w_out^T (2:4 along D), out woutT [D][R]
__global__ __launch_bounds__(256) void prep_kernel(
    const float* __restrict__ x, f16* __restrict__ xh, int n8,
    const float* __restrict__ Wi, f16* __restrict__ winT, const float* __restrict__ sci,
    const float* __restrict__ Wo, f16* __restrict__ woutT, const float* __restrict__ sco,
    int D, int R, int nCastB, int nSpInB)
{
    int b = blockIdx.x;
    int tid = threadIdx.x;
    if (b < nCastB) {
        int i = b * 256 + tid;
        if (i < n8) {
            float4 a = reinterpret_cast<const float4*>(x)[2 * i];
            float4 c = reinterpret_cast<const float4*>(x)[2 * i + 1];
            f16x8 o = {(f16)a.x, (f16)a.y, (f16)a.z, (f16)a.w,
                       (f16)c.x, (f16)c.y, (f16)c.z, (f16)c.w};
            reinterpret_cast<f16x8*>(xh)[i] = o;
        }
    } else if (b < nCastB + nSpInB) {
        int t = (b - nCastB) * 256 + tid;   // t = rg*D + d (coalesced writes)
        int RG = R >> 2;
        if (t >= RG * D) return;
        int rg = t / D, d = t - rg * D;
        float s = *sci;
        float4 w = *reinterpret_cast<const float4*>(Wi + (size_t)d * R + rg * 4);
        float a0 = fabsf(w.x), a1 = fabsf(w.y), a2 = fabsf(w.z), a3 = fabsf(w.w);
        float thr = thr4(a0, a1, a2, a3);
        size_t base = (size_t)(rg * 4) * D + d;
        winT[base]                 = (f16)soft1(a0, thr, w.x, s);
        winT[base + D]             = (f16)soft1(a1, thr, w.y, s);
        winT[base + 2 * (size_t)D] = (f16)soft1(a2, thr, w.z, s);
        winT[base + 3 * (size_t)D] = (f16)soft1(a3, thr, w.w, s);
    } else {
        int t = (b - nCastB - nSpInB) * 256 + tid;  // t = dg*R + r
        if (t >= (D >> 2) * R) return;
        int dg = t / R, r = t - dg * R;
        float s = *sco;
        size_t i0 = (size_t)(dg * 4) * R + r;
        float w0 = Wo[i0], w1 = Wo[i0 + R], w2 = Wo[i0 + 2 * (size_t)R], w3 = Wo[i0 + 3 * (size_t)R];
        float a0 = fabsf(w0), a1 = fabsf(w1), a2 = fabsf(w2), a3 = fabsf(w3);
        float thr = thr4(a0, a1, a2, a3);
        woutT[i0]                 = (f16)soft1(a0, thr, w0, s);
        woutT[i0 + R]             = (f16)soft1(a1, thr, w1, s);
        woutT[i0 + 2 * (size_t)R] = (f16)soft1(a2, thr, w2, s);
        woutT[i0 + 3 * (size_t)R] = (f16)soft1(a3, thr, w3, s);
    }
}

// C[M][N] = A[M][K] f16 @ Bt[N][K]^T f16, fp32 accum.
// Tile TBM x TBN, 4 waves in 2x2 grid (wave tile TBM/2 x TBN/2).
// Depth-2 double-buffered pipeline with COUNTED vmcnt (T4): raw s_barrier,
// never drain vmcnt to 0 in the steady state. Per K-step:
//   vmcnt(L) -> s_barrier          : tile t landed (tile t+1 stays in flight)
//   ds_read frags (buf t&1)
//   lgkmcnt(0) -> sched_barrier(0) : rule-18 fence (MFMA must not hoist)
//   s_barrier                      : all waves done reading buf t&1
//   STAGE(buf t&1, tile t+2)       : overwrite released buffer, async
//   MFMA                           : overlaps tile t+1/t+2 loads
// XCD-aware bijective swizzle: each XCD owns a contiguous band of M-tiles.
template <int TBM, int TBN, typename OT, bool BIAS>
__global__ __launch_bounds__(256) void gemm_bt(
    const f16* __restrict__ A, const f16* __restrict__ Bt, OT* __restrict__ C,
    const float* __restrict__ bias, int M, int N, int K)
{
    constexpr int MI = TBM / 32;   // A-fragments per wave
    constexpr int NF = TBN / 32;   // B-fragments per wave
    constexpr int HM = TBM / 2;    // per-wave M span
    constexpr int HN = TBN / 2;    // per-wave N span
    constexpr int L  = TBM / 64 + TBN / 64;  // g2l16 per thread per tile
    __shared__ f16 As[2][TBM * BK];
    __shared__ f16 Bs[2][TBN * BK];

    const int tid  = threadIdx.x;
    const int lane = tid & 63;
    const int w    = tid >> 6;
    const int wm   = w & 1;
    const int wn   = w >> 1;
    const int l16  = lane & 15;
    const int quad = lane >> 4;

    // XCD swizzle: HW round-robins consecutive dispatches across 8 XCDs.
    const int nbx = N / TBN;
    const int nb  = gridDim.x;
    int d = blockIdx.x;
    int wgid = ((nb & 7) == 0) ? ((d & 7) * (nb >> 3) + (d >> 3)) : d;
    int by = wgid / nbx;
    int bx = wgid - by * nbx;
    const int bm = by * TBM;
    const int bn = bx * TBN;

    // one g2l16 by a full wave covers 16 rows x 32 halves:
    // row = lane>>2, col = (lane&3)*8
    const int srow = lane >> 2;
    const int scol = (lane & 3) * 8;
    const f16* gA = A  + (size_t)(bm + w * (TBM / 4) + srow) * K + scol;
    const f16* gB = Bt + (size_t)(bn + w * (TBN / 4) + srow) * K + scol;

    f32x4 acc[MI][NF] = {};

    auto STAGE = [&](int buf, int t) {
        const int k0 = t * BK;
        f16* lA = &As[buf][(w * (TBM / 4)) * BK];
        f16* lB = &Bs[buf][(w * (TBN / 4)) * BK];
#pragma unroll
        for (int i = 0; i < TBM / 64; ++i)
            g2l16(gA + k0 + i * 16 * (size_t)K, lA + i * 16 * BK);
#pragma unroll
        for (int i = 0; i < TBN / 64; ++i)
            g2l16(gB + k0 + i * 16 * (size_t)K, lB + i * 16 * BK);
    };

    auto LOADFRAG = [&](int buf, f16x8* af, f16x8* bf) {
#pragma unroll
        for (int m = 0; m < MI; ++m)
            af[m] = *reinterpret_cast<const f16x8*>(
                &As[buf][(wm * HM + m * 16 + l16) * BK + quad * 8]);
#pragma unroll
        for (int n = 0; n < NF; ++n)
            bf[n] = *reinterpret_cast<const f16x8*>(
                &Bs[buf][(wn * HN + n * 16 + l16) * BK + quad * 8]);
    };

    auto MFMA_ALL = [&](f16x8* af, f16x8* bf) {
#pragma unroll
        for (int m = 0; m < MI; ++m)
#pragma unroll
            for (int n = 0; n < NF; ++n)
                acc[m][n] = __builtin_amdgcn_mfma_f32_16x16x32_f16(af[m], bf[n], acc[m][n], 0, 0, 0);
    };

    const int nk = K / BK;   // 64 for GEMM1, 16 for GEMM2 (>= 4, even)
    STAGE(0, 0);
    STAGE(1, 1);
    for (int t = 0; t < nk - 2; ++t) {
        wait_vmcnt<L>();                       // tile t landed; t+1 in flight
        __builtin_amdgcn_s_barrier();
        __builtin_amdgcn_sched_barrier(0);
        f16x8 af[MI], bf[NF];
        LOADFRAG(t & 1, af, bf);
        asm volatile("s_waitcnt lgkmcnt(0)" ::: "memory");
        __builtin_amdgcn_sched_barrier(0);     // rule 18
        __builtin_amdgcn_s_barrier();          // buf (t&1) released by all waves
        STAGE(t & 1, t + 2);                   // async overwrite; overlaps MFMA
        MFMA_ALL(af, bf);
    }
    {   // t = nk-2: tiles nk-2, nk-1 in flight, nothing left to stage
        wait_vmcnt<L>();
        __builtin_amdgcn_s_barrier();
        __builtin_amdgcn_sched_barrier(0);
        f16x8 af[MI], bf[NF];
        LOADFRAG(nk & 1, af, bf);              // (nk-2)&1
        MFMA_ALL(af, bf);
    }
    {   // t = nk-1: drain fully
        wait_vmcnt<0>();
        __builtin_amdgcn_s_barrier();
        __builtin_amdgcn_sched_barrier(0);
        f16x8 af[MI], bf[NF];
        LOADFRAG((nk - 1) & 1, af, bf);
        MFMA_ALL(af, bf);
    }

    // epilogue: C/D layout row = quad*4 + r, col = lane&15
#pragma unroll
    for (int m = 0; m < MI; ++m) {
        int row_base = bm + wm * HM + m * 16 + quad * 4;
#pragma unroll
        for (int n = 0; n < NF; ++n) {
            int col = bn + wn * HN + n * 16 + l16;
            float b = BIAS ? bias[col] : 0.0f;
#pragma unroll
            for (int r = 0; r < 4; ++r) {
                float v = acc[m][n][r];
                size_t idx = (size_t)(row_base + r) * N + col;
                if constexpr (BIAS) C[idx] = (OT)(v + b);
                else                C[idx] = (OT)v;
            }
        }
    }
}

extern "C" void kernel_launch(void* const* d_in, const int* in_sizes, int n_in,
                              void* d_out, int out_size, void* d_ws, size_t ws_size,
                              hipStream_t stream)
{
    const float* x      = (const float*)d_in[0];
    const float* w_in   = (const float*)d_in[1];
    const float* w_out  = (const float*)d_in[2];
    const float* bias   = (const float*)d_in[3];
    const float* sc_in  = (const float*)d_in[4];
    const float* sc_out = (const float*)d_in[5];

    const int D = in_sizes[3];            // 2048
    const int R = in_sizes[1] / D;        // 512
    const int M = in_sizes[0] / D;        // 8192 (B*S)

    f16* winT  = (f16*)d_ws;                      // [R][D]
    f16* woutT = winT + (size_t)R * D;            // [D][R]
    f16* h     = woutT + (size_t)D * R;           // [M][R]
    f16* xh    = h + (size_t)M * R;               // [M][D]
    float* out = (float*)d_out;

    const int n8 = M * D / 8;
    const int nCastB  = (n8 + 255) / 256;
    const int nSpInB  = ((R / 4) * D + 255) / 256;
    const int nSpOutB = ((D / 4) * R + 255) / 256;
    prep_kernel<<<nCastB + nSpInB + nSpOutB, 256, 0, stream>>>(
        x, xh, n8, w_in, winT, sc_in, w_out, woutT, sc_out, D, R, nCastB, nSpInB);

    // GEMM1: M=8192, N=512, K=2048. 64x128 tile, 512 blocks = 2/CU.
    gemm_bt<64, 128, f16, false><<<(R / 128) * (M / 64), 256, 0, stream>>>(
        xh, winT, h, nullptr, M, R, D);
    // GEMM2: M=8192, N=2048, K=512. 128x128 tile (16 MFMA : 8 ds_read per
    // K-step), 1024 blocks = 4/CU.
    gemm_bt<128, 128, float, true><<<(D / 128) * (M / 128), 256, 0, stream>>>(
        h, woutT, out, bias, M, D, R);
}